// Round 2
// baseline (732.932 us; speedup 1.0000x reference)
//
#include <hip/hip_runtime.h>
#include <math.h>

#define NV   6890
#define NJ   24
#define NB   10
#define NPF  207
#define NCJ  19
#define BATCHN 1024
#define NC3  (NV*3)     // 20670
#define KTOT 224        // 207 pose + 10 beta + 7 zero pad

#define OUT_JOINTS_OFF (BATCHN*NV*3)
#define OUT_RS_OFF     (OUT_JOINTS_OFF + BATCHN*NCJ*3)

// ws float offsets
#define WS_JS    0                        // [24][33]
#define WS_AADJ  1024                     // [1024][24][12] f32
#define WS_EF    (WS_AADJ + BATCHN*288)   // [1024][224] bf16 (ushort)

typedef __attribute__((ext_vector_type(8))) short short8;
typedef __attribute__((ext_vector_type(4))) float f32x4;

__device__ __forceinline__ unsigned short f2bf(float f) {
    unsigned u = __float_as_uint(f);
    unsigned r = u + 0x7FFFu + ((u >> 16) & 1u);   // RNE
    return (unsigned short)(r >> 16);
}

// ---------------- Kernel A: fold J_regressor into shapedirs/v_template ----
__global__ void smpl_kA(const float* __restrict__ jreg, const float* __restrict__ sdirs,
                        const float* __restrict__ vtmpl, float* __restrict__ js) {
    int j = blockIdx.x;
    int tid = threadIdx.x;  // 256
    float acc[33];
#pragma unroll
    for (int e = 0; e < 33; e++) acc[e] = 0.f;
    for (int v = tid; v < NV; v += 256) {
        float w = jreg[j * NV + v];
#pragma unroll
        for (int k = 0; k < NB; k++) {
#pragma unroll
            for (int d = 0; d < 3; d++)
                acc[k * 3 + d] += w * sdirs[(size_t)k * NC3 + v * 3 + d];
        }
#pragma unroll
        for (int d = 0; d < 3; d++) acc[30 + d] += w * vtmpl[v * 3 + d];
    }
#pragma unroll
    for (int e = 0; e < 33; e++) {
#pragma unroll
        for (int off = 32; off >= 1; off >>= 1) acc[e] += __shfl_xor(acc[e], off, 64);
    }
    __shared__ float red[4][33];
    int lane = tid & 63, wv = tid >> 6;
    if (lane == 0) {
#pragma unroll
        for (int e = 0; e < 33; e++) red[wv][e] = acc[e];
    }
    __syncthreads();
    if (tid < 33) js[j * 33 + tid] = red[0][tid] + red[1][tid] + red[2][tid] + red[3][tid];
}

// ---------------- Kernel B: Rodrigues + chain + bf16 feature pack ---------
__global__ void smpl_kB(const float* __restrict__ theta, const float* __restrict__ beta_,
                        const float* __restrict__ js, float* __restrict__ outRs,
                        unsigned short* __restrict__ ef, float* __restrict__ aadj) {
    int b = blockIdx.x;
    int t = threadIdx.x;  // 64
    __shared__ float Rl[NJ][9];
    __shared__ float Jl[NJ][3];
    __shared__ float Rw[NJ][12];

    if (t < NJ) {
        int j = t;
        float tx = theta[b * 72 + j * 3 + 0];
        float ty = theta[b * 72 + j * 3 + 1];
        float tz = theta[b * 72 + j * 3 + 2];
        float ax = tx + 1e-8f, ay = ty + 1e-8f, az = tz + 1e-8f;
        float ang = sqrtf(ax * ax + ay * ay + az * az);
        float inv = 1.0f / ang;
        float rx = tx * inv, ry = ty * inv, rz = tz * inv;
        float s = sinf(ang), c = cosf(ang), t1 = 1.0f - c;
        float R[9];
        R[0] = 1.0f - t1 * (ry * ry + rz * rz);
        R[1] = -s * rz + t1 * rx * ry;
        R[2] =  s * ry + t1 * rx * rz;
        R[3] =  s * rz + t1 * rx * ry;
        R[4] = 1.0f - t1 * (rx * rx + rz * rz);
        R[5] = -s * rx + t1 * ry * rz;
        R[6] = -s * ry + t1 * rx * rz;
        R[7] =  s * rx + t1 * ry * rz;
        R[8] = 1.0f - t1 * (rx * rx + ry * ry);
#pragma unroll
        for (int e = 0; e < 9; e++) {
            Rl[j][e] = R[e];
            outRs[(size_t)b * 216 + j * 9 + e] = R[e];
        }
#pragma unroll
        for (int d = 0; d < 3; d++) {
            float accJ = js[j * 33 + 30 + d];
#pragma unroll
            for (int k = 0; k < NB; k++) accJ += beta_[b * NB + k] * js[j * 33 + k * 3 + d];
            Jl[j][d] = accJ;
        }
    }
    __syncthreads();
    // bf16 extended features: [0..206] pose_feature, [207..216] beta, rest 0
    for (int e = t; e < KTOT; e += 64) {
        float val;
        if (e < NPF) {
            int j = e / 9 + 1;
            int rc = e - (j - 1) * 9;
            val = Rl[j][rc] - ((rc == 0 || rc == 4 || rc == 8) ? 1.0f : 0.0f);
        } else if (e < NPF + NB) {
            val = beta_[b * NB + (e - NPF)];
        } else val = 0.f;
        ef[(size_t)b * KTOT + e] = f2bf(val);
    }
    if (t == 0) {
#pragma unroll
        for (int r = 0; r < 3; r++) {
            Rw[0][r * 4 + 0] =  Rl[0][r * 3 + 0];
            Rw[0][r * 4 + 1] = -Rl[0][r * 3 + 1];
            Rw[0][r * 4 + 2] = -Rl[0][r * 3 + 2];
            Rw[0][r * 4 + 3] =  Jl[0][r];
        }
        const int par[NJ] = {0,0,0,0,1,2,3,4,5,6,7,8,9,9,9,12,13,14,16,17,18,19,20,21};
#pragma unroll
        for (int i = 1; i < NJ; i++) {
            int p = par[i];
            float tr0 = Jl[i][0] - Jl[p][0];
            float tr1 = Jl[i][1] - Jl[p][1];
            float tr2 = Jl[i][2] - Jl[p][2];
#pragma unroll
            for (int r = 0; r < 3; r++) {
                float p0 = Rw[p][r * 4 + 0], p1 = Rw[p][r * 4 + 1], p2 = Rw[p][r * 4 + 2];
#pragma unroll
                for (int cc = 0; cc < 3; cc++)
                    Rw[i][r * 4 + cc] = p0 * Rl[i][0 + cc] + p1 * Rl[i][3 + cc] + p2 * Rl[i][6 + cc];
                Rw[i][r * 4 + 3] = p0 * tr0 + p1 * tr1 + p2 * tr2 + Rw[p][r * 4 + 3];
            }
        }
    }
    __syncthreads();
    for (int e = t; e < NJ * 12; e += 64) {
        int j = e / 12, rc = e % 12, r = rc >> 2, cc = rc & 3;
        float v;
        if (cc < 3) v = Rw[j][rc];
        else v = Rw[j][r * 4 + 3] - (Rw[j][r * 4 + 0] * Jl[j][0] + Rw[j][r * 4 + 1] * Jl[j][1] +
                                     Rw[j][r * 4 + 2] * Jl[j][2]);
        aadj[(size_t)b * 288 + e] = v;
    }
}

// ---------------- Kernel C: MFMA pose-GEMM + f32 skinning -----------------
// tile: 64 batches x 32 verts (96 cols), K = 224 in 7 steps of 32
__global__ __launch_bounds__(256, 4) void smpl_kC(
    const float* __restrict__ pdirs, const float* __restrict__ sdirs,
    const float* __restrict__ vtmpl, const unsigned short* __restrict__ ef,
    const float* __restrict__ aadj, const float* __restrict__ wts,
    float* __restrict__ outv) {
    __shared__ unsigned short dlds[96][40];   // dirs^T tile, pad 40 (2-way free)
    __shared__ float vph[3][32][66];          // v_posed, [d][v][b] (2-way free)
    __shared__ float wls[NJ][36];             // weights^T

    int tid = threadIdx.x;
    int vtile = blockIdx.x;
    int btile = blockIdx.y * 64;
    int lane = tid & 63, wv = tid >> 6;
    int l15 = lane & 15, lg = lane >> 4;

    // stage weights (perfectly coalesced: wts index = vtile*768 + e)
    for (int e = tid; e < NJ * 32; e += 256) {
        int vl = e / 24, j = e - vl * 24;
        int gv = vtile * 32 + vl;
        wls[j][vl] = (gv < NV) ? wts[(size_t)vtile * 768 + e] : 0.f;
    }

    // A-fragments for all 7 K-steps resident in registers
    const short8* efr = (const short8*)(ef + (size_t)(btile + wv * 16 + l15) * KTOT);
    short8 afr[7];
#pragma unroll
    for (int ks = 0; ks < 7; ks++) afr[ks] = efr[ks * 4 + lg];

    f32x4 acc[6];
#pragma unroll
    for (int s = 0; s < 6; s++) acc[s] = (f32x4){0.f, 0.f, 0.f, 0.f};

    for (int ks = 0; ks < 7; ks++) {
        if (tid < 192) {   // stage dirs^T slice: 32 k x 96 cols, f32->bf16
            int cq = tid % 24, q = tid / 24;   // col-quad, k-quad
            int kk0 = q * 4;
            int c0 = cq * 4;
            int gc = vtile * 96 + c0;
            unsigned short pk[4][4];
#pragma unroll
            for (int i = 0; i < 4; i++) {
                int k = ks * 32 + kk0 + i;
                const float* src = (k < NPF) ? (pdirs + (size_t)k * NC3)
                                 : (k < NPF + NB) ? (sdirs + (size_t)(k - NPF) * NC3)
                                 : (const float*)0;
                float f0 = 0, f1 = 0, f2 = 0, f3 = 0;
                if (src && gc + 1 < NC3) { float2 u = *(const float2*)(src + gc);     f0 = u.x; f1 = u.y; }
                if (src && gc + 3 < NC3) { float2 u = *(const float2*)(src + gc + 2); f2 = u.x; f3 = u.y; }
                pk[i][0] = f2bf(f0); pk[i][1] = f2bf(f1); pk[i][2] = f2bf(f2); pk[i][3] = f2bf(f3);
            }
#pragma unroll
            for (int cc = 0; cc < 4; cc++) {
                unsigned lo = (unsigned)pk[0][cc] | ((unsigned)pk[1][cc] << 16);
                unsigned hi = (unsigned)pk[2][cc] | ((unsigned)pk[3][cc] << 16);
                *(uint2*)&dlds[c0 + cc][kk0] = make_uint2(lo, hi);
            }
        }
        __syncthreads();
        short8 av = afr[ks];
#pragma unroll
        for (int s = 0; s < 6; s++) {
            short8 bv = *(const short8*)&dlds[s * 16 + l15][lg * 8];
            acc[s] = __builtin_amdgcn_mfma_f32_16x16x32_bf16(av, bv, acc[s], 0, 0, 0);
        }
        __syncthreads();
    }

    // epilogue: v_posed = acc + v_template -> vph[d][v][b]
#pragma unroll
    for (int s = 0; s < 6; s++) {
        int col = s * 16 + l15;
        int gcol = vtile * 96 + col;
        float vt = (gcol < NC3) ? vtmpl[gcol] : 0.f;
        int v = col / 3, d = col - v * 3;
#pragma unroll
        for (int r = 0; r < 4; r++) {
            int bl = wv * 16 + lg * 4 + r;
            vph[d][v][bl] = acc[s][r] + vt;
        }
    }
    __syncthreads();

    // phase 2: skinning. thread = (b, vert-octet); Aadj global (lane-dedup'd)
    int pb = tid >> 2, pq = tid & 3, pv = pq * 8;
    float x0[8], x1[8], x2[8];
#pragma unroll
    for (int v = 0; v < 8; v++) {
        x0[v] = vph[0][pv + v][pb];
        x1[v] = vph[1][pv + v][pb];
        x2[v] = vph[2][pv + v][pb];
    }
    __syncthreads();
    float ac[8][3];
#pragma unroll
    for (int v = 0; v < 8; v++) { ac[v][0] = 0.f; ac[v][1] = 0.f; ac[v][2] = 0.f; }
    const float* ab = aadj + (size_t)(btile + pb) * 288;
#pragma unroll 4
    for (int j = 0; j < NJ; j++) {
        float4 A0 = *(const float4*)(ab + j * 12);
        float4 A1 = *(const float4*)(ab + j * 12 + 4);
        float4 A2 = *(const float4*)(ab + j * 12 + 8);
        float w[8];
        *(float4*)&w[0] = *(const float4*)&wls[j][pv];
        *(float4*)&w[4] = *(const float4*)&wls[j][pv + 4];
#pragma unroll
        for (int v = 0; v < 8; v++) {
            float tx = fmaf(A0.x, x0[v], fmaf(A0.y, x1[v], fmaf(A0.z, x2[v], A0.w)));
            float ty = fmaf(A1.x, x0[v], fmaf(A1.y, x1[v], fmaf(A1.z, x2[v], A1.w)));
            float tz = fmaf(A2.x, x0[v], fmaf(A2.y, x1[v], fmaf(A2.z, x2[v], A2.w)));
            ac[v][0] = fmaf(w[v], tx, ac[v][0]);
            ac[v][1] = fmaf(w[v], ty, ac[v][1]);
            ac[v][2] = fmaf(w[v], tz, ac[v][2]);
        }
    }
    // write results back to vph, then coalesced global store
#pragma unroll
    for (int v = 0; v < 8; v++) {
        vph[0][pv + v][pb] = ac[v][0];
        vph[1][pv + v][pb] = ac[v][1];
        vph[2][pv + v][pb] = ac[v][2];
    }
    __syncthreads();
    int b2 = tid >> 2, ch = tid & 3;
    int colb = ch * 24;
    float* orow = outv + (size_t)(btile + b2) * NC3 + vtile * 96 + colb;
    int gcb = vtile * 96 + colb;
#pragma unroll
    for (int p = 0; p < 12; p++) {
        const int i0 = 2 * p, i1 = 2 * p + 1;
        float va = vph[i0 % 3][ch * 8 + i0 / 3][b2];
        float vb = vph[i1 % 3][ch * 8 + i1 / 3][b2];
        if (gcb + i1 < NC3) *(float2*)(orow + i0) = make_float2(va, vb);
    }
}

// ---------------- Kernel D: COCO joint regression (8 batches/block) -------
__global__ void smpl_kD(const float* __restrict__ verts, const float* __restrict__ jr,
                        float* __restrict__ outj) {
    int bq = threadIdx.x >> 5, vs = threadIdx.x & 31;
    int b = blockIdx.x * 8 + bq;
    float acc[NCJ][3];
#pragma unroll
    for (int j = 0; j < NCJ; j++) { acc[j][0] = 0.f; acc[j][1] = 0.f; acc[j][2] = 0.f; }
    const float* vb = verts + (size_t)b * NC3;
    for (int v = vs; v < NV; v += 32) {
        float x = vb[v * 3 + 0], y = vb[v * 3 + 1], z = vb[v * 3 + 2];
#pragma unroll
        for (int j = 0; j < NCJ; j++) {
            float w = jr[(size_t)j * NV + v];
            acc[j][0] = fmaf(w, x, acc[j][0]);
            acc[j][1] = fmaf(w, y, acc[j][1]);
            acc[j][2] = fmaf(w, z, acc[j][2]);
        }
    }
#pragma unroll
    for (int j = 0; j < NCJ; j++)
#pragma unroll
        for (int d = 0; d < 3; d++) {
            float s = acc[j][d];
#pragma unroll
            for (int off = 16; off >= 1; off >>= 1) s += __shfl_xor(s, off, 64);
            acc[j][d] = s;
        }
    if (vs == 0) {
#pragma unroll
        for (int j = 0; j < NCJ; j++) {
            outj[(size_t)b * 57 + j * 3 + 0] = acc[j][0];
            outj[(size_t)b * 57 + j * 3 + 1] = acc[j][1];
            outj[(size_t)b * 57 + j * 3 + 2] = acc[j][2];
        }
    }
}

extern "C" void kernel_launch(void* const* d_in, const int* in_sizes, int n_in,
                              void* d_out, int out_size, void* d_ws, size_t ws_size,
                              hipStream_t stream) {
    (void)in_sizes; (void)n_in; (void)out_size; (void)ws_size;
    const float* beta       = (const float*)d_in[0];
    const float* theta      = (const float*)d_in[1];
    const float* v_template = (const float*)d_in[2];
    const float* shapedirs  = (const float*)d_in[3];
    const float* jreg       = (const float*)d_in[4];
    const float* posedirs   = (const float*)d_in[5];
    const float* jointreg   = (const float*)d_in[6];
    const float* weights    = (const float*)d_in[7];
    float* out = (float*)d_out;
    float* ws  = (float*)d_ws;
    unsigned short* ef = (unsigned short*)(ws + WS_EF);

    smpl_kA<<<NJ, 256, 0, stream>>>(jreg, shapedirs, v_template, ws + WS_JS);
    smpl_kB<<<BATCHN, 64, 0, stream>>>(theta, beta, ws + WS_JS, out + OUT_RS_OFF,
                                       ef, ws + WS_AADJ);
    dim3 gC(216, 16);
    smpl_kC<<<gC, 256, 0, stream>>>(posedirs, shapedirs, v_template, ef,
                                    ws + WS_AADJ, weights, out);
    smpl_kD<<<128, 256, 0, stream>>>(out, jointreg, out + OUT_JOINTS_OFF);
}

// Round 3
// 387.798 us; speedup vs baseline: 1.8900x; 1.8900x over previous
//
#include <hip/hip_runtime.h>
#include <math.h>

#define NV   6890
#define NJ   24
#define NB   10
#define NPF  207
#define NCJ  19
#define BATCHN 1024
#define NC3  (NV*3)     // 20670
#define KTOT 224        // 207 pose + 10 beta + 7 zero pad

#define OUT_JOINTS_OFF (BATCHN*NV*3)
#define OUT_RS_OFF     (OUT_JOINTS_OFF + BATCHN*NCJ*3)

// ws float offsets
#define WS_JS     0        // [24][33] f32
#define WS_EF     1024     // [1024][224] bf16 (ushort)
#define WS_AADJT  115712   // [1024][16][32] bf16 (ushort)

typedef __attribute__((ext_vector_type(8))) short short8;
typedef __attribute__((ext_vector_type(4))) float f32x4;

__device__ __forceinline__ unsigned short f2bf(float f) {
    unsigned u = __float_as_uint(f);
    unsigned r = u + 0x7FFFu + ((u >> 16) & 1u);   // RNE
    return (unsigned short)(r >> 16);
}

// ---------------- Kernel A: fold J_regressor into shapedirs/v_template ----
__global__ void smpl_kA(const float* __restrict__ jreg, const float* __restrict__ sdirs,
                        const float* __restrict__ vtmpl, float* __restrict__ js) {
    int j = blockIdx.x;
    int tid = threadIdx.x;  // 256
    float acc[33];
#pragma unroll
    for (int e = 0; e < 33; e++) acc[e] = 0.f;
    for (int v = tid; v < NV; v += 256) {
        float w = jreg[j * NV + v];
#pragma unroll
        for (int k = 0; k < NB; k++) {
#pragma unroll
            for (int d = 0; d < 3; d++)
                acc[k * 3 + d] += w * sdirs[(size_t)k * NC3 + v * 3 + d];
        }
#pragma unroll
        for (int d = 0; d < 3; d++) acc[30 + d] += w * vtmpl[v * 3 + d];
    }
#pragma unroll
    for (int e = 0; e < 33; e++) {
#pragma unroll
        for (int off = 32; off >= 1; off >>= 1) acc[e] += __shfl_xor(acc[e], off, 64);
    }
    __shared__ float red[4][33];
    int lane = tid & 63, wv = tid >> 6;
    if (lane == 0) {
#pragma unroll
        for (int e = 0; e < 33; e++) red[wv][e] = acc[e];
    }
    __syncthreads();
    if (tid < 33) js[j * 33 + tid] = red[0][tid] + red[1][tid] + red[2][tid] + red[3][tid];
}

// ---------------- Kernel B: Rodrigues + chain + bf16 packs ----------------
__global__ void smpl_kB(const float* __restrict__ theta, const float* __restrict__ beta_,
                        const float* __restrict__ js, float* __restrict__ outRs,
                        unsigned short* __restrict__ ef, unsigned short* __restrict__ aadjT) {
    int b = blockIdx.x;
    int t = threadIdx.x;  // 64
    __shared__ float Rl[NJ][9];
    __shared__ float Jl[NJ][3];
    __shared__ float Rw[NJ][12];

    if (t < NJ) {
        int j = t;
        float tx = theta[b * 72 + j * 3 + 0];
        float ty = theta[b * 72 + j * 3 + 1];
        float tz = theta[b * 72 + j * 3 + 2];
        float ax = tx + 1e-8f, ay = ty + 1e-8f, az = tz + 1e-8f;
        float ang = sqrtf(ax * ax + ay * ay + az * az);
        float inv = 1.0f / ang;
        float rx = tx * inv, ry = ty * inv, rz = tz * inv;
        float s = sinf(ang), c = cosf(ang), t1 = 1.0f - c;
        float R[9];
        R[0] = 1.0f - t1 * (ry * ry + rz * rz);
        R[1] = -s * rz + t1 * rx * ry;
        R[2] =  s * ry + t1 * rx * rz;
        R[3] =  s * rz + t1 * rx * ry;
        R[4] = 1.0f - t1 * (rx * rx + rz * rz);
        R[5] = -s * rx + t1 * ry * rz;
        R[6] = -s * ry + t1 * rx * rz;
        R[7] =  s * rx + t1 * ry * rz;
        R[8] = 1.0f - t1 * (rx * rx + ry * ry);
#pragma unroll
        for (int e = 0; e < 9; e++) {
            Rl[j][e] = R[e];
            outRs[(size_t)b * 216 + j * 9 + e] = R[e];
        }
#pragma unroll
        for (int d = 0; d < 3; d++) {
            float accJ = js[j * 33 + 30 + d];
#pragma unroll
            for (int k = 0; k < NB; k++) accJ += beta_[b * NB + k] * js[j * 33 + k * 3 + d];
            Jl[j][d] = accJ;
        }
    }
    __syncthreads();
    // bf16 extended features: [0..206] pose_feature, [207..216] beta, rest 0
    for (int e = t; e < KTOT; e += 64) {
        float val;
        if (e < NPF) {
            int j = e / 9 + 1;
            int rc = e - (j - 1) * 9;
            val = Rl[j][rc] - ((rc == 0 || rc == 4 || rc == 8) ? 1.0f : 0.0f);
        } else if (e < NPF + NB) {
            val = beta_[b * NB + (e - NPF)];
        } else val = 0.f;
        ef[(size_t)b * KTOT + e] = f2bf(val);
    }
    if (t == 0) {
#pragma unroll
        for (int r = 0; r < 3; r++) {
            Rw[0][r * 4 + 0] =  Rl[0][r * 3 + 0];
            Rw[0][r * 4 + 1] = -Rl[0][r * 3 + 1];
            Rw[0][r * 4 + 2] = -Rl[0][r * 3 + 2];
            Rw[0][r * 4 + 3] =  Jl[0][r];
        }
        const int par[NJ] = {0,0,0,0,1,2,3,4,5,6,7,8,9,9,9,12,13,14,16,17,18,19,20,21};
#pragma unroll
        for (int i = 1; i < NJ; i++) {
            int p = par[i];
            float tr0 = Jl[i][0] - Jl[p][0];
            float tr1 = Jl[i][1] - Jl[p][1];
            float tr2 = Jl[i][2] - Jl[p][2];
#pragma unroll
            for (int r = 0; r < 3; r++) {
                float p0 = Rw[p][r * 4 + 0], p1 = Rw[p][r * 4 + 1], p2 = Rw[p][r * 4 + 2];
#pragma unroll
                for (int cc = 0; cc < 3; cc++)
                    Rw[i][r * 4 + cc] = p0 * Rl[i][0 + cc] + p1 * Rl[i][3 + cc] + p2 * Rl[i][6 + cc];
                Rw[i][r * 4 + 3] = p0 * tr0 + p1 * tr1 + p2 * tr2 + Rw[p][r * 4 + 3];
            }
        }
    }
    __syncthreads();
    // aadjT[b][n(16)][k(32)] bf16: n = p*4+q indexes A row-major 3x4, k = joint
    for (int i = t; i < 512; i += 64) {
        int n = i >> 5, k = i & 31;
        float v = 0.f;
        if (n < 12 && k < 24) {
            int r = n >> 2, cc = n & 3;
            if (cc < 3) v = Rw[k][n];
            else v = Rw[k][r * 4 + 3] - (Rw[k][r * 4 + 0] * Jl[k][0] + Rw[k][r * 4 + 1] * Jl[k][1] +
                                         Rw[k][r * 4 + 2] * Jl[k][2]);
        }
        aadjT[(size_t)b * 512 + i] = f2bf(v);
    }
}

// ---------------- Kernel C: resident-dirs MFMA GEMM + MFMA T-blend --------
// block owns 32 verts (96 cols); loops over 8 btiles of 64 batches.
__global__ __launch_bounds__(256, 2) void smpl_kC(
    const float* __restrict__ pdirs, const float* __restrict__ sdirs,
    const float* __restrict__ vtmpl, const unsigned short* __restrict__ ef,
    const unsigned short* __restrict__ aadjT, const float* __restrict__ wts,
    float* __restrict__ outv) {
    __shared__ unsigned short dlds[96][232];   // dirs^T, pad 232 (bank stride 20 -> 2-way)
    __shared__ float vph[3 * 2113];            // v_posed [d][v*66 + b], d-stride 2113
    __shared__ unsigned short wbf[32][32];     // weights bf16 [v][k], k padded to 32

    int tid = threadIdx.x;
    int vtile = blockIdx.x;
    int lane = tid & 63, wv = tid >> 6;
    int l15 = lane & 15, lg = lane >> 4;

    // stage dirs once: 224 k x 96 cols, f32 -> bf16
    for (int e = tid; e < KTOT * 96; e += 256) {
        int k = e / 96, c = e - k * 96;
        int gc = vtile * 96 + c;
        float val = 0.f;
        if (gc < NC3) {
            if (k < NPF) val = pdirs[(size_t)k * NC3 + gc];
            else if (k < NPF + NB) val = sdirs[(size_t)(k - NPF) * NC3 + gc];
        }
        dlds[c][k] = f2bf(val);
    }
    // stage weights bf16 [32 v][32 k]
    for (int e = tid; e < 32 * 32; e += 256) {
        int vl = e >> 5, k = e & 31;
        int gv = vtile * 32 + vl;
        float w = (k < NJ && gv < NV) ? wts[(size_t)gv * NJ + k] : 0.f;
        wbf[vl][k] = f2bf(w);
    }
    __syncthreads();
    // after this barrier all LDS except vph is read-only; vph use is wave-local.

    // loop-invariant fragments / values
    short8 wf0 = *(const short8*)&wbf[l15][lg * 8];
    short8 wf1 = *(const short8*)&wbf[16 + l15][lg * 8];
    float vt[6];
#pragma unroll
    for (int s = 0; s < 6; s++) {
        int gcol = vtile * 96 + s * 16 + l15;
        vt[s] = (gcol < NC3) ? vtmpl[gcol] : 0.f;
    }

    for (int bt = 0; bt < 8; bt++) {
        int btile = (blockIdx.y * 8 + bt) * 64;
        // ---- pose+shape GEMM: 64 batches x 96 cols, K=224 ----
        const short8* efr = (const short8*)(ef + (size_t)(btile + wv * 16 + l15) * KTOT);
        f32x4 acc[6];
#pragma unroll
        for (int s = 0; s < 6; s++) acc[s] = (f32x4){0.f, 0.f, 0.f, 0.f};
#pragma unroll
        for (int ks = 0; ks < 7; ks++) {
            short8 av = efr[ks * 4 + lg];
#pragma unroll
            for (int s = 0; s < 6; s++) {
                short8 bv = *(const short8*)&dlds[s * 16 + l15][ks * 32 + lg * 8];
                acc[s] = __builtin_amdgcn_mfma_f32_16x16x32_bf16(av, bv, acc[s], 0, 0, 0);
            }
        }
        // ---- epilogue: vph = acc + v_template (wave-local batches) ----
#pragma unroll
        for (int s = 0; s < 6; s++) {
            int col = s * 16 + l15;
            int v = col / 3, d = col - v * 3;
#pragma unroll
            for (int r = 0; r < 4; r++) {
                int bl = wv * 16 + lg * 4 + r;
                vph[d * 2113 + v * 66 + bl] = acc[s][r] + vt[s];
            }
        }
        // ---- skinning: per-batch MFMA T-blend, in-lane apply ----
        // C[row=n, col=vert]: lane(l15,lg) holds T[p=lg][q=0..3] for vert l15.
        const short8* at0 = (const short8*)(aadjT + (size_t)(btile + wv * 16) * 512);
        short8 afn = at0[l15 * 4 + lg];
#pragma unroll
        for (int bl2 = 0; bl2 < 16; bl2++) {
            short8 af = afn;
            if (bl2 < 15) afn = at0[(bl2 + 1) * 64 + l15 * 4 + lg];
            f32x4 z = (f32x4){0.f, 0.f, 0.f, 0.f};
            f32x4 t0 = __builtin_amdgcn_mfma_f32_16x16x32_bf16(af, wf0, z, 0, 0, 0);
            f32x4 t1 = __builtin_amdgcn_mfma_f32_16x16x32_bf16(af, wf1, z, 0, 0, 0);
            int b = btile + wv * 16 + bl2;
            int wvb = wv * 16 + bl2;
            if (lg < 3) {
                int p = lg;
                {
                    int vv = l15;
                    float x0 = vph[0 * 2113 + vv * 66 + wvb];
                    float x1 = vph[1 * 2113 + vv * 66 + wvb];
                    float x2 = vph[2 * 2113 + vv * 66 + wvb];
                    float o = fmaf(t0[0], x0, fmaf(t0[1], x1, fmaf(t0[2], x2, t0[3])));
                    int gv = vtile * 32 + vv;
                    if (gv < NV) outv[(size_t)b * NC3 + gv * 3 + p] = o;
                }
                {
                    int vv = 16 + l15;
                    float x0 = vph[0 * 2113 + vv * 66 + wvb];
                    float x1 = vph[1 * 2113 + vv * 66 + wvb];
                    float x2 = vph[2 * 2113 + vv * 66 + wvb];
                    float o = fmaf(t1[0], x0, fmaf(t1[1], x1, fmaf(t1[2], x2, t1[3])));
                    int gv = vtile * 32 + vv;
                    if (gv < NV) outv[(size_t)b * NC3 + gv * 3 + p] = o;
                }
            }
        }
    }
}

// ---------------- Kernel D: COCO joint regression (8 batches/block) -------
__global__ void smpl_kD(const float* __restrict__ verts, const float* __restrict__ jr,
                        float* __restrict__ outj) {
    int bq = threadIdx.x >> 5, vs = threadIdx.x & 31;
    int b = blockIdx.x * 8 + bq;
    float acc[NCJ][3];
#pragma unroll
    for (int j = 0; j < NCJ; j++) { acc[j][0] = 0.f; acc[j][1] = 0.f; acc[j][2] = 0.f; }
    const float* vb = verts + (size_t)b * NC3;
    for (int v = vs; v < NV; v += 32) {
        float x = vb[v * 3 + 0], y = vb[v * 3 + 1], z = vb[v * 3 + 2];
#pragma unroll
        for (int j = 0; j < NCJ; j++) {
            float w = jr[(size_t)j * NV + v];
            acc[j][0] = fmaf(w, x, acc[j][0]);
            acc[j][1] = fmaf(w, y, acc[j][1]);
            acc[j][2] = fmaf(w, z, acc[j][2]);
        }
    }
#pragma unroll
    for (int j = 0; j < NCJ; j++)
#pragma unroll
        for (int d = 0; d < 3; d++) {
            float s = acc[j][d];
#pragma unroll
            for (int off = 16; off >= 1; off >>= 1) s += __shfl_xor(s, off, 64);
            acc[j][d] = s;
        }
    if (vs == 0) {
#pragma unroll
        for (int j = 0; j < NCJ; j++) {
            outj[(size_t)b * 57 + j * 3 + 0] = acc[j][0];
            outj[(size_t)b * 57 + j * 3 + 1] = acc[j][1];
            outj[(size_t)b * 57 + j * 3 + 2] = acc[j][2];
        }
    }
}

extern "C" void kernel_launch(void* const* d_in, const int* in_sizes, int n_in,
                              void* d_out, int out_size, void* d_ws, size_t ws_size,
                              hipStream_t stream) {
    (void)in_sizes; (void)n_in; (void)out_size; (void)ws_size;
    const float* beta       = (const float*)d_in[0];
    const float* theta      = (const float*)d_in[1];
    const float* v_template = (const float*)d_in[2];
    const float* shapedirs  = (const float*)d_in[3];
    const float* jreg       = (const float*)d_in[4];
    const float* posedirs   = (const float*)d_in[5];
    const float* jointreg   = (const float*)d_in[6];
    const float* weights    = (const float*)d_in[7];
    float* out = (float*)d_out;
    float* ws  = (float*)d_ws;
    unsigned short* ef    = (unsigned short*)(ws + WS_EF);
    unsigned short* aadjT = (unsigned short*)(ws + WS_AADJT);

    smpl_kA<<<NJ, 256, 0, stream>>>(jreg, shapedirs, v_template, ws + WS_JS);
    smpl_kB<<<BATCHN, 64, 0, stream>>>(theta, beta, ws + WS_JS, out + OUT_RS_OFF,
                                       ef, aadjT);
    dim3 gC(216, 2);
    smpl_kC<<<gC, 256, 0, stream>>>(posedirs, shapedirs, v_template, ef,
                                    aadjT, weights, out);
    smpl_kD<<<128, 256, 0, stream>>>(out, jointreg, out + OUT_JOINTS_OFF);
}

// Round 4
// 163.888 us; speedup vs baseline: 4.4722x; 2.3662x over previous
//
#include <hip/hip_runtime.h>
#include <math.h>

#define NV   6890
#define NJ   24
#define NB   10
#define NPF  207
#define NCJ  19
#define BATCHN 1024
#define NC3  (NV*3)     // 20670
#define KTOT 224        // 207 pose + 10 beta + 7 zero pad

#define OUT_JOINTS_OFF (BATCHN*NV*3)
#define OUT_RS_OFF     (OUT_JOINTS_OFF + BATCHN*NCJ*3)

// ws float offsets
#define WS_JS     0        // [24][33] f32
#define WS_EF     1024     // [1024][224] bf16 (ushort)
#define WS_AADJT  115712   // [1024][16][32] bf16 (ushort)

typedef __attribute__((ext_vector_type(8))) short short8;
typedef __attribute__((ext_vector_type(4))) float f32x4;

__device__ __forceinline__ unsigned short f2bf(float f) {
    unsigned u = __float_as_uint(f);
    unsigned r = u + 0x7FFFu + ((u >> 16) & 1u);   // RNE
    return (unsigned short)(r >> 16);
}

// ---------------- Kernel A: fold J_regressor into shapedirs/v_template ----
__global__ void smpl_kA(const float* __restrict__ jreg, const float* __restrict__ sdirs,
                        const float* __restrict__ vtmpl, float* __restrict__ js) {
    int j = blockIdx.x;
    int tid = threadIdx.x;  // 256
    float acc[33];
#pragma unroll
    for (int e = 0; e < 33; e++) acc[e] = 0.f;
    for (int v = tid; v < NV; v += 256) {
        float w = jreg[j * NV + v];
#pragma unroll
        for (int k = 0; k < NB; k++) {
#pragma unroll
            for (int d = 0; d < 3; d++)
                acc[k * 3 + d] += w * sdirs[(size_t)k * NC3 + v * 3 + d];
        }
#pragma unroll
        for (int d = 0; d < 3; d++) acc[30 + d] += w * vtmpl[v * 3 + d];
    }
#pragma unroll
    for (int e = 0; e < 33; e++) {
#pragma unroll
        for (int off = 32; off >= 1; off >>= 1) acc[e] += __shfl_xor(acc[e], off, 64);
    }
    __shared__ float red[4][33];
    int lane = tid & 63, wv = tid >> 6;
    if (lane == 0) {
#pragma unroll
        for (int e = 0; e < 33; e++) red[wv][e] = acc[e];
    }
    __syncthreads();
    if (tid < 33) js[j * 33 + tid] = red[0][tid] + red[1][tid] + red[2][tid] + red[3][tid];
}

// ---------------- Kernel B: Rodrigues + chain + bf16 packs ----------------
__global__ void smpl_kB(const float* __restrict__ theta, const float* __restrict__ beta_,
                        const float* __restrict__ js, float* __restrict__ outRs,
                        unsigned short* __restrict__ ef, unsigned short* __restrict__ aadjT) {
    int b = blockIdx.x;
    int t = threadIdx.x;  // 64
    __shared__ float Rl[NJ][9];
    __shared__ float Jl[NJ][3];
    __shared__ float Rw[NJ][12];

    if (t < NJ) {
        int j = t;
        float tx = theta[b * 72 + j * 3 + 0];
        float ty = theta[b * 72 + j * 3 + 1];
        float tz = theta[b * 72 + j * 3 + 2];
        float ax = tx + 1e-8f, ay = ty + 1e-8f, az = tz + 1e-8f;
        float ang = sqrtf(ax * ax + ay * ay + az * az);
        float inv = 1.0f / ang;
        float rx = tx * inv, ry = ty * inv, rz = tz * inv;
        float s = sinf(ang), c = cosf(ang), t1 = 1.0f - c;
        float R[9];
        R[0] = 1.0f - t1 * (ry * ry + rz * rz);
        R[1] = -s * rz + t1 * rx * ry;
        R[2] =  s * ry + t1 * rx * rz;
        R[3] =  s * rz + t1 * rx * ry;
        R[4] = 1.0f - t1 * (rx * rx + rz * rz);
        R[5] = -s * rx + t1 * ry * rz;
        R[6] = -s * ry + t1 * rx * rz;
        R[7] =  s * rx + t1 * ry * rz;
        R[8] = 1.0f - t1 * (rx * rx + ry * ry);
#pragma unroll
        for (int e = 0; e < 9; e++) {
            Rl[j][e] = R[e];
            outRs[(size_t)b * 216 + j * 9 + e] = R[e];
        }
#pragma unroll
        for (int d = 0; d < 3; d++) {
            float accJ = js[j * 33 + 30 + d];
#pragma unroll
            for (int k = 0; k < NB; k++) accJ += beta_[b * NB + k] * js[j * 33 + k * 3 + d];
            Jl[j][d] = accJ;
        }
    }
    __syncthreads();
    // bf16 extended features: [0..206] pose_feature, [207..216] beta, rest 0
    for (int e = t; e < KTOT; e += 64) {
        float val;
        if (e < NPF) {
            int j = e / 9 + 1;
            int rc = e - (j - 1) * 9;
            val = Rl[j][rc] - ((rc == 0 || rc == 4 || rc == 8) ? 1.0f : 0.0f);
        } else if (e < NPF + NB) {
            val = beta_[b * NB + (e - NPF)];
        } else val = 0.f;
        ef[(size_t)b * KTOT + e] = f2bf(val);
    }
    if (t == 0) {
#pragma unroll
        for (int r = 0; r < 3; r++) {
            Rw[0][r * 4 + 0] =  Rl[0][r * 3 + 0];
            Rw[0][r * 4 + 1] = -Rl[0][r * 3 + 1];
            Rw[0][r * 4 + 2] = -Rl[0][r * 3 + 2];
            Rw[0][r * 4 + 3] =  Jl[0][r];
        }
        const int par[NJ] = {0,0,0,0,1,2,3,4,5,6,7,8,9,9,9,12,13,14,16,17,18,19,20,21};
#pragma unroll
        for (int i = 1; i < NJ; i++) {
            int p = par[i];
            float tr0 = Jl[i][0] - Jl[p][0];
            float tr1 = Jl[i][1] - Jl[p][1];
            float tr2 = Jl[i][2] - Jl[p][2];
#pragma unroll
            for (int r = 0; r < 3; r++) {
                float p0 = Rw[p][r * 4 + 0], p1 = Rw[p][r * 4 + 1], p2 = Rw[p][r * 4 + 2];
#pragma unroll
                for (int cc = 0; cc < 3; cc++)
                    Rw[i][r * 4 + cc] = p0 * Rl[i][0 + cc] + p1 * Rl[i][3 + cc] + p2 * Rl[i][6 + cc];
                Rw[i][r * 4 + 3] = p0 * tr0 + p1 * tr1 + p2 * tr2 + Rw[p][r * 4 + 3];
            }
        }
    }
    __syncthreads();
    // aadjT[b][n(16)][k(32)] bf16: n = p*4+q indexes A row-major 3x4, k = joint
    for (int i = t; i < 512; i += 64) {
        int n = i >> 5, k = i & 31;
        float v = 0.f;
        if (n < 12 && k < 24) {
            int r = n >> 2, cc = n & 3;
            if (cc < 3) v = Rw[k][n];
            else v = Rw[k][r * 4 + 3] - (Rw[k][r * 4 + 0] * Jl[k][0] + Rw[k][r * 4 + 1] * Jl[k][1] +
                                         Rw[k][r * 4 + 2] * Jl[k][2]);
        }
        aadjT[(size_t)b * 512 + i] = f2bf(v);
    }
}

// ---------------- Kernel C: resident-dirs MFMA GEMM + MFMA T-blend --------
// block owns 32 verts (96 cols); loops over 8 btiles of 64 batches.
__global__ __launch_bounds__(256, 2) void smpl_kC(
    const float* __restrict__ pdirs, const float* __restrict__ sdirs,
    const float* __restrict__ vtmpl, const unsigned short* __restrict__ ef,
    const unsigned short* __restrict__ aadjT, const float* __restrict__ wts,
    float* __restrict__ outv) {
    __shared__ unsigned short dlds[96][232];   // dirs^T, pad 232 (bank stride 20 -> 2-way)
    __shared__ float vph[3 * 2113];            // v_posed [d][v*66 + b], d-stride 2113
    __shared__ unsigned short wbf[32][32];     // weights bf16 [v][k], k padded to 32

    int tid = threadIdx.x;
    int vtile = blockIdx.x;
    int lane = tid & 63, wv = tid >> 6;
    int l15 = lane & 15, lg = lane >> 4;

    // stage dirs once: 224 k x 96 cols, f32 -> bf16
    for (int e = tid; e < KTOT * 96; e += 256) {
        int k = e / 96, c = e - k * 96;
        int gc = vtile * 96 + c;
        float val = 0.f;
        if (gc < NC3) {
            if (k < NPF) val = pdirs[(size_t)k * NC3 + gc];
            else if (k < NPF + NB) val = sdirs[(size_t)(k - NPF) * NC3 + gc];
        }
        dlds[c][k] = f2bf(val);
    }
    // stage weights bf16 [32 v][32 k]
    for (int e = tid; e < 32 * 32; e += 256) {
        int vl = e >> 5, k = e & 31;
        int gv = vtile * 32 + vl;
        float w = (k < NJ && gv < NV) ? wts[(size_t)gv * NJ + k] : 0.f;
        wbf[vl][k] = f2bf(w);
    }
    __syncthreads();
    // after this barrier all LDS except vph is read-only; vph use is wave-local.

    // loop-invariant fragments / values
    short8 wf0 = *(const short8*)&wbf[l15][lg * 8];
    short8 wf1 = *(const short8*)&wbf[16 + l15][lg * 8];
    float vt[6];
#pragma unroll
    for (int s = 0; s < 6; s++) {
        int gcol = vtile * 96 + s * 16 + l15;
        vt[s] = (gcol < NC3) ? vtmpl[gcol] : 0.f;
    }

    for (int bt = 0; bt < 8; bt++) {
        int btile = (blockIdx.y * 8 + bt) * 64;
        // ---- pose+shape GEMM: 64 batches x 96 cols, K=224 ----
        const short8* efr = (const short8*)(ef + (size_t)(btile + wv * 16 + l15) * KTOT);
        f32x4 acc[6];
#pragma unroll
        for (int s = 0; s < 6; s++) acc[s] = (f32x4){0.f, 0.f, 0.f, 0.f};
#pragma unroll
        for (int ks = 0; ks < 7; ks++) {
            short8 av = efr[ks * 4 + lg];
#pragma unroll
            for (int s = 0; s < 6; s++) {
                short8 bv = *(const short8*)&dlds[s * 16 + l15][ks * 32 + lg * 8];
                acc[s] = __builtin_amdgcn_mfma_f32_16x16x32_bf16(av, bv, acc[s], 0, 0, 0);
            }
        }
        // ---- epilogue: vph = acc + v_template (wave-local batches) ----
#pragma unroll
        for (int s = 0; s < 6; s++) {
            int col = s * 16 + l15;
            int v = col / 3, d = col - v * 3;
#pragma unroll
            for (int r = 0; r < 4; r++) {
                int bl = wv * 16 + lg * 4 + r;
                vph[d * 2113 + v * 66 + bl] = acc[s][r] + vt[s];
            }
        }
        // ---- skinning: per-batch MFMA T-blend, in-lane apply ----
        // C[row=n, col=vert]: lane(l15,lg) holds T[p=lg][q=0..3] for vert l15.
        const short8* at0 = (const short8*)(aadjT + (size_t)(btile + wv * 16) * 512);
        short8 afn = at0[l15 * 4 + lg];
#pragma unroll
        for (int bl2 = 0; bl2 < 16; bl2++) {
            short8 af = afn;
            if (bl2 < 15) afn = at0[(bl2 + 1) * 64 + l15 * 4 + lg];
            f32x4 z = (f32x4){0.f, 0.f, 0.f, 0.f};
            f32x4 t0 = __builtin_amdgcn_mfma_f32_16x16x32_bf16(af, wf0, z, 0, 0, 0);
            f32x4 t1 = __builtin_amdgcn_mfma_f32_16x16x32_bf16(af, wf1, z, 0, 0, 0);
            int b = btile + wv * 16 + bl2;
            int wvb = wv * 16 + bl2;
            if (lg < 3) {
                int p = lg;
                {
                    int vv = l15;
                    float x0 = vph[0 * 2113 + vv * 66 + wvb];
                    float x1 = vph[1 * 2113 + vv * 66 + wvb];
                    float x2 = vph[2 * 2113 + vv * 66 + wvb];
                    float o = fmaf(t0[0], x0, fmaf(t0[1], x1, fmaf(t0[2], x2, t0[3])));
                    int gv = vtile * 32 + vv;
                    if (gv < NV) outv[(size_t)b * NC3 + gv * 3 + p] = o;
                }
                {
                    int vv = 16 + l15;
                    float x0 = vph[0 * 2113 + vv * 66 + wvb];
                    float x1 = vph[1 * 2113 + vv * 66 + wvb];
                    float x2 = vph[2 * 2113 + vv * 66 + wvb];
                    float o = fmaf(t1[0], x0, fmaf(t1[1], x1, fmaf(t1[2], x2, t1[3])));
                    int gv = vtile * 32 + vv;
                    if (gv < NV) outv[(size_t)b * NC3 + gv * 3 + p] = o;
                }
            }
        }
    }
}

// ---------------- Kernel D: COCO joint regression, 2 batches/thread -------
// 512 blocks x 256 threads. Thread covers 2 verts x 2 batches per iter;
// 6890 verts = 3445 float2-pairs (exact). jr loads shared across batches.
__global__ __launch_bounds__(256) void smpl_kD(
    const float* __restrict__ verts, const float* __restrict__ jr,
    float* __restrict__ outj) {
    int tid = threadIdx.x;
    int b0 = blockIdx.x * 2;
    const float* va = verts + (size_t)b0 * NC3;
    const float* vb = va + NC3;
    float acc[2][NCJ][3];
#pragma unroll
    for (int g = 0; g < 2; g++)
#pragma unroll
        for (int j = 0; j < NCJ; j++) { acc[g][j][0] = 0.f; acc[g][j][1] = 0.f; acc[g][j][2] = 0.f; }

    for (int it = 0; it < 14; it++) {
        int v2 = it * 256 + tid;
        if (v2 < 3445) {
            int v = v2 * 2;
            const float* pa = va + v * 3;
            const float* pb = vb + v * 3;
            float2 a0 = *(const float2*)(pa);      // x0 y0
            float2 a1 = *(const float2*)(pa + 2);  // z0 x1
            float2 a2 = *(const float2*)(pa + 4);  // y1 z1
            float2 c0 = *(const float2*)(pb);
            float2 c1 = *(const float2*)(pb + 2);
            float2 c2 = *(const float2*)(pb + 4);
#pragma unroll
            for (int j = 0; j < NCJ; j++) {
                float2 w = *(const float2*)(jr + (size_t)j * NV + v);
                acc[0][j][0] = fmaf(w.x, a0.x, fmaf(w.y, a1.y, acc[0][j][0]));
                acc[0][j][1] = fmaf(w.x, a0.y, fmaf(w.y, a2.x, acc[0][j][1]));
                acc[0][j][2] = fmaf(w.x, a1.x, fmaf(w.y, a2.y, acc[0][j][2]));
                acc[1][j][0] = fmaf(w.x, c0.x, fmaf(w.y, c1.y, acc[1][j][0]));
                acc[1][j][1] = fmaf(w.x, c0.y, fmaf(w.y, c2.x, acc[1][j][1]));
                acc[1][j][2] = fmaf(w.x, c1.x, fmaf(w.y, c2.y, acc[1][j][2]));
            }
        }
    }
    // wave reduction (64-wide butterfly) on 114 values
#pragma unroll
    for (int g = 0; g < 2; g++)
#pragma unroll
        for (int j = 0; j < NCJ; j++)
#pragma unroll
            for (int d = 0; d < 3; d++) {
                float s = acc[g][j][d];
#pragma unroll
                for (int off = 32; off >= 1; off >>= 1) s += __shfl_xor(s, off, 64);
                acc[g][j][d] = s;
            }
    __shared__ float red[4][114];
    int lane = tid & 63, wv = tid >> 6;
    if (lane == 0) {
#pragma unroll
        for (int g = 0; g < 2; g++)
#pragma unroll
            for (int j = 0; j < NCJ; j++)
#pragma unroll
                for (int d = 0; d < 3; d++)
                    red[wv][g * 57 + j * 3 + d] = acc[g][j][d];
    }
    __syncthreads();
    if (tid < 114) {
        float s = red[0][tid] + red[1][tid] + red[2][tid] + red[3][tid];
        int g = tid / 57, i = tid - g * 57;
        outj[(size_t)(b0 + g) * 57 + i] = s;
    }
}

extern "C" void kernel_launch(void* const* d_in, const int* in_sizes, int n_in,
                              void* d_out, int out_size, void* d_ws, size_t ws_size,
                              hipStream_t stream) {
    (void)in_sizes; (void)n_in; (void)out_size; (void)ws_size;
    const float* beta       = (const float*)d_in[0];
    const float* theta      = (const float*)d_in[1];
    const float* v_template = (const float*)d_in[2];
    const float* shapedirs  = (const float*)d_in[3];
    const float* jreg       = (const float*)d_in[4];
    const float* posedirs   = (const float*)d_in[5];
    const float* jointreg   = (const float*)d_in[6];
    const float* weights    = (const float*)d_in[7];
    float* out = (float*)d_out;
    float* ws  = (float*)d_ws;
    unsigned short* ef    = (unsigned short*)(ws + WS_EF);
    unsigned short* aadjT = (unsigned short*)(ws + WS_AADJT);

    smpl_kA<<<NJ, 256, 0, stream>>>(jreg, shapedirs, v_template, ws + WS_JS);
    smpl_kB<<<BATCHN, 64, 0, stream>>>(theta, beta, ws + WS_JS, out + OUT_RS_OFF,
                                       ef, aadjT);
    dim3 gC(216, 2);
    smpl_kC<<<gC, 256, 0, stream>>>(posedirs, shapedirs, v_template, ef,
                                    aadjT, weights, out);
    smpl_kD<<<512, 256, 0, stream>>>(out, jointreg, out + OUT_JOINTS_OFF);
}